// Round 2
// baseline (821.783 us; speedup 1.0000x reference)
//
#include <hip/hip_runtime.h>
#include <hip/hip_cooperative_groups.h>
#include <math.h>

namespace cg = cooperative_groups;

#define TWO_G 19.6f   // 2*9.8, matches jnp's folded 2.0*G constant
#define NPART 256     // partial-sum rows (== grid size of the mid phase)

__device__ __forceinline__ float flow_q(float th, float d, float a) {
    // matches reference association: (theta * sqrt(2*G*h)) * area
    return th * sqrtf(TWO_G * d) * a;
}

__device__ __forceinline__ float wave_sum(float v) {
#pragma unroll
    for (int o = 32; o > 0; o >>= 1) v += __shfl_xor(v, o);
    return v;
}

// uniform-index broadcast (j is wave-uniform at each use site)
__device__ __forceinline__ float lane_bcast(float v, int j) {
    return __int_as_float(__builtin_amdgcn_readlane(__float_as_int(v), j));
}

// ---------------- register-sourced serial solve (layer0 + fallback path) --------
__device__ __forceinline__ float solve_serial(float H, float inflow, int lane,
                                              float2 (&sv)[16], float (&tv)[16],
                                              float* acc) {
    float h0 = lane_bcast(sv[0].x, 0);
    float a0 = lane_bcast(sv[0].y, 0);
    float t0 = lane_bcast(tv[0], 0);
    float d0 = (H + inflow) - h0;
    float q0 = (d0 > 0.0f) ? flow_q(t0, d0, a0) : 0.0f;
    float cum = q0;
    float u   = H - 0.5f * cum;
    if (lane == 0 && q0 != 0.0f) atomicAdd(&acc[0], q0);

#pragma unroll
    for (int c = 0; c < 16; ++c) {
        float2 s = sv[c];
        unsigned long long avail = (c == 0) ? ~1ull : ~0ull;   // spigot 0 already done
        unsigned long long cand  = __ballot(s.x < u) & avail;
        float qmine = 0.0f;
        while (cand) {
            int j = __builtin_ctzll(cand);
            float hj = lane_bcast(s.x, j);
            float aj = lane_bcast(s.y, j);
            float tj = lane_bcast(tv[c], j);
            float d = u - hj;                    // > 0 by ballot
            float q = flow_q(tj, d, aj);
            cum += q;
            u = H - 0.5f * cum;
            if (lane == j) qmine = q;
            if (j >= 63) break;
            avail &= (~0ull << (j + 1));
            cand = __ballot(s.x < u) & avail;    // u decreased: subset of old cand
        }
        if (qmine != 0.0f) atomicAdd(&acc[c * 64 + lane], qmine);
    }
    return cum;
}

// ---------------- LDS-sourced serial solve (fused mid layers) --------------------
// Identical arithmetic/order to solve_serial; data routed global->reg->LDS->reg is
// bit-exact. 1-chunk-ahead ds_read prefetch hides LDS latency off the serial chain.
__device__ __forceinline__ float solve_lds(float H, float inflow, int lane,
                                           const char* buf, float* acc) {
    const float2* Sb = (const float2*)buf;          // 1024 float2, row layout
    const float*  Tb = (const float*)(buf + 8192);  // 1024 float

    float2 s_cur = Sb[lane];
    float  t_cur = Tb[lane];

    float h0 = lane_bcast(s_cur.x, 0);
    float a0 = lane_bcast(s_cur.y, 0);
    float t0 = lane_bcast(t_cur, 0);
    float d0 = (H + inflow) - h0;
    float q0 = (d0 > 0.0f) ? flow_q(t0, d0, a0) : 0.0f;
    float cum = q0;
    float u   = H - 0.5f * cum;
    if (lane == 0 && q0 != 0.0f) atomicAdd(&acc[0], q0);

#pragma unroll
    for (int c = 0; c < 16; ++c) {
        float2 s = s_cur;
        float  t = t_cur;
        if (c < 15) {                               // prefetch next chunk off-chain
            s_cur = Sb[(c + 1) * 64 + lane];
            t_cur = Tb[(c + 1) * 64 + lane];
        }
        unsigned long long avail = (c == 0) ? ~1ull : ~0ull;
        unsigned long long cand  = __ballot(s.x < u) & avail;
        float qmine = 0.0f;
        while (cand) {
            int j = __builtin_ctzll(cand);
            float hj = lane_bcast(s.x, j);
            float aj = lane_bcast(s.y, j);
            float tj = lane_bcast(t, j);
            float d = u - hj;
            float q = flow_q(tj, d, aj);
            cum += q;
            u = H - 0.5f * cum;
            if (lane == j) qmine = q;
            if (j >= 63) break;
            avail &= (~0ull << (j + 1));
            cand = __ballot(s.x < u) & avail;
        }
        if (qmine != 0.0f) atomicAdd(&acc[c * 64 + lane], qmine);
    }
    return cum;
}

// ---- layer 0: single head bucket, 1024 spigots, one wave; dense q row -> P0 ----
__device__ __forceinline__ void layer0_body(const float* __restrict__ H0p,
                                            const float* __restrict__ S0,
                                            const float* __restrict__ theta0,
                                            const float* __restrict__ precip,
                                            float* __restrict__ out,
                                            float* __restrict__ P0, int lane) {
    const float H  = H0p[0];
    const float pl = precip[0] * 0.0625f;        // precip / 16 (exact)
    const float2* S2 = (const float2*)S0;
    float2 sv[16]; float tv[16];
#pragma unroll
    for (int c = 0; c < 16; ++c) { sv[c] = S2[c * 64 + lane]; tv[c] = theta0[c * 64 + lane]; }

    float h0 = lane_bcast(sv[0].x, 0);
    float a0 = lane_bcast(sv[0].y, 0);
    float t0 = lane_bcast(tv[0], 0);
    float d0 = (H + pl) - h0;
    float q0 = (d0 > 0.0f) ? flow_q(t0, d0, a0) : 0.0f;
    float cum = q0;
    float u   = H - 0.5f * cum;
    if (lane == 0) P0[0] = q0;

#pragma unroll
    for (int c = 0; c < 16; ++c) {
        int i = c * 64 + lane;
        float2 s = sv[c];
        unsigned long long avail = (c == 0) ? ~1ull : ~0ull;
        unsigned long long cand  = __ballot(s.x < u) & avail;
        float qmine = 0.0f;
        while (cand) {
            int j = __builtin_ctzll(cand);
            float hj = lane_bcast(s.x, j);
            float aj = lane_bcast(s.y, j);
            float tj = lane_bcast(tv[c], j);
            float d = u - hj;
            float q = flow_q(tj, d, aj);
            cum += q;
            u = H - 0.5f * cum;
            if (lane == j) qmine = q;
            if (j >= 63) break;
            avail &= (~0ull << (j + 1));
            cand = __ballot(s.x < u) & avail;
        }
        if (i > 0) P0[i] = qmine;
    }
    if (lane == 0) out[0] = (H - cum) + pl;      // H0_new
}

// ---- the whole cascade: 1 cooperative kernel, 256 blocks (1/CU), 15 grid syncs --
// T14 staging: layer l+1's S/theta rows are loaded global->REG (48 VGPR, one set)
// during layer l's solve, then ds_written into this wave's LDS slot at layer end.
// Solve reads the CURRENT layer from LDS chunk-by-chunk => no double register
// buffer, no demotion (round-1 failure: VGPR_Count=84 < 96 needed => scratch).
__global__ __launch_bounds__(256, 1)
void cascade_kernel(const float* __restrict__ H0p, const float* __restrict__ Hmid,
                    const float* __restrict__ Hlast, const float* __restrict__ S0,
                    const float* __restrict__ Smid, const float* __restrict__ Slast,
                    const float* __restrict__ th0, const float* __restrict__ thmid,
                    const float* __restrict__ thlast, const float* __restrict__ precip,
                    float* __restrict__ out, float* __restrict__ PA, float* __restrict__ PB)
{
    cg::grid_group grid = cg::this_grid();
    __shared__ float acc[1024];
    __shared__ __align__(16) char sbuf[4][12288];   // per-wave: S row 8 KB + theta 4 KB
    const int tid  = threadIdx.x;
    const int lane = tid & 63;
    const int w    = tid >> 6;
    const int bid  = blockIdx.x;
    const int b    = bid * 4 + w;                   // bucket<->wave mapping (unchanged)

#pragma unroll
    for (int r = 0; r < 4; ++r) acc[r * 256 + tid] = 0.0f;

    const float pb = precip[0] * (0.0625f / 1024.0f);   // exact: 2^-14 * precip

    float4 stS[8]; float4 stT[4];                   // the single in-flight staging set

    // ---- pre-loop: stage mid layer 0 for this wave's bucket ----
    {
        const float4* gS = (const float4*)(Smid + (size_t)b * 2048);
        const float4* gT = (const float4*)(thmid + (size_t)b * 1024);
#pragma unroll
        for (int i = 0; i < 8; ++i) stS[i] = gS[i * 64 + lane];
#pragma unroll
        for (int i = 0; i < 4; ++i) stT[i] = gT[i * 64 + lane];
    }
    // head bucket runs on block 0 / wave 0 while its staging loads fly
    if (bid == 0 && w == 0)
        layer0_body(H0p, S0, th0, precip, out, PA, lane);
    {
        float4* lS = (float4*)&sbuf[w][0];
        float4* lT = (float4*)&sbuf[w][8192];
#pragma unroll
        for (int i = 0; i < 8; ++i) lS[i * 64 + lane] = stS[i];
#pragma unroll
        for (int i = 0; i < 4; ++i) lT[i * 64 + lane] = stT[i];
    }
    grid.sync();

#pragma unroll 1
    for (int l = 0; l < 14; ++l) {
        const float* Pin = (l & 1) ? PB : PA;
        float*       Pou = (l & 1) ? PA : PB;

        // 1) inflow gather issued FIRST -> its waitcnt leaves staging in flight
        float part = 0.0f;
        if (l == 0) {
            if (lane == 0) part = Pin[b];           // layer0 wrote a single row
        } else {
#pragma unroll
            for (int k = 0; k < 4; ++k) part += Pin[(size_t)(k * 64 + lane) * 1024 + b];
        }
        const float H = Hmid[(size_t)l * 1024 + b];

        // 2) issue next layer's staging loads (12x dwordx4/lane, retired at ds_write)
        if (l < 13) {
            const float4* gS = (const float4*)(Smid + (size_t)(l + 1) * 2097152 + (size_t)b * 2048);
            const float4* gT = (const float4*)(thmid + (size_t)(l + 1) * 1048576 + (size_t)b * 1024);
#pragma unroll
            for (int i = 0; i < 8; ++i) stS[i] = gS[i * 64 + lane];
#pragma unroll
            for (int i = 0; i < 4; ++i) stT[i] = gT[i * 64 + lane];
        }

        // 3) reduce + serial solve from LDS (staging loads overlap this)
        const float inflow = pb + wave_sum(part);
        const float cum    = solve_lds(H, inflow, lane, sbuf[w], acc);
        if (lane == 0) out[1 + (size_t)l * 1024 + b] = (H - cum) + inflow;

        __syncthreads();
#pragma unroll
        for (int r = 0; r < 4; ++r) {
            const int idx = r * 256 + tid;
            Pou[(size_t)bid * 1024 + idx] = acc[idx];
            acc[idx] = 0.0f;                        // re-arm for next layer
        }

        // 4) write-late: staged regs -> this wave's LDS slot (per-wave in-order DS
        //    guarantees the solve's reads completed; no cross-wave sharing)
        if (l < 13) {
            float4* lS = (float4*)&sbuf[w][0];
            float4* lT = (float4*)&sbuf[w][8192];
#pragma unroll
            for (int i = 0; i < 8; ++i) lS[i * 64 + lane] = stS[i];
#pragma unroll
            for (int i = 0; i < 4; ++i) lT[i * 64 + lane] = stT[i];
        }
        grid.sync();                                // includes block barrier + dev fence
    }

    // ---- last layer: 1 spigot per bucket (l=13 wrote PA) ----
    {
        float part = 0.0f;
#pragma unroll
        for (int k = 0; k < 4; ++k) part += PA[(size_t)(k * 64 + lane) * 1024 + b];
        const float inflow = pb + wave_sum(part);
        if (lane == 0) {
            const float  Hv = Hlast[b];
            const float2 s  = ((const float2*)Slast)[b];
            const float  d  = (Hv + inflow) - s.x;
            const float  q  = (d > 0.0f) ? flow_q(thlast[b], d, s.y) : 0.0f;
            out[1 + 14 * 1024 + b]        = (Hv - q) + inflow;   // H_last_new
            out[1 + 14 * 1024 + 1024 + b] = q;                   // q_last
        }
    }
}

// ================= fallback: 16-kernel pipeline (round-0 numerics) ==============
__device__ __forceinline__ void prefetch_row(const float2* __restrict__ S2,
                                             const float* __restrict__ th, int lane,
                                             float2 (&sv)[16], float (&tv)[16]) {
#pragma unroll
    for (int c = 0; c < 16; ++c) { sv[c] = S2[c * 64 + lane]; tv[c] = th[c * 64 + lane]; }
}

__global__ __launch_bounds__(64)
void layer0_kernel(const float* __restrict__ H0p, const float* __restrict__ S0,
                   const float* __restrict__ theta0, const float* __restrict__ precip,
                   float* __restrict__ out, float* __restrict__ P0)
{
    layer0_body(H0p, S0, theta0, precip, out, P0, threadIdx.x);
}

__global__ __launch_bounds__(256)
void mid_kernel(const float* __restrict__ Hl, const float* __restrict__ Sl,
                const float* __restrict__ thl, const float* __restrict__ Pin,
                int npart, float* __restrict__ Pout, float* __restrict__ outl,
                const float* __restrict__ precip)
{
    __shared__ float acc[1024];
    const int tid  = threadIdx.x;
    const int lane = tid & 63;
    const int b    = blockIdx.x * 4 + (tid >> 6);

#pragma unroll
    for (int r = 0; r < 4; ++r) acc[r * 256 + tid] = 0.0f;
    __syncthreads();

    const float pb = precip[0] * (0.0625f / 1024.0f);

    float part = 0.0f;
    for (int k = lane; k < npart; k += 64) part += Pin[(size_t)k * 1024 + b];

    float2 sv[16]; float tv[16];
    prefetch_row((const float2*)Sl + (size_t)b * 1024, thl + (size_t)b * 1024, lane, sv, tv);

    const float H      = Hl[b];
    const float inflow = pb + wave_sum(part);
    const float cum    = solve_serial(H, inflow, lane, sv, tv, acc);
    if (lane == 0) outl[b] = (H - cum) + inflow;

    __syncthreads();
#pragma unroll
    for (int r = 0; r < 4; ++r)
        Pout[(size_t)blockIdx.x * 1024 + r * 256 + tid] = acc[r * 256 + tid];
}

__global__ __launch_bounds__(256)
void last_kernel(const float* __restrict__ Hlast, const float* __restrict__ Slast,
                 const float* __restrict__ thlast, const float* __restrict__ Pin,
                 const float* __restrict__ precip, float* __restrict__ out)
{
    const int lane = threadIdx.x & 63;
    const int b    = blockIdx.x * 4 + (threadIdx.x >> 6);
    const float pb = precip[0] * (0.0625f / 1024.0f);

    float part = 0.0f;
#pragma unroll
    for (int k = 0; k < NPART / 64; ++k) part += Pin[(size_t)(k * 64 + lane) * 1024 + b];
    float inflow = pb + wave_sum(part);

    if (lane == 0) {
        float H = Hlast[b];
        float2 s = ((const float2*)Slast)[b];
        float d = (H + inflow) - s.x;
        float q = (d > 0.0f) ? flow_q(thlast[b], d, s.y) : 0.0f;
        out[1 + 14 * 1024 + b]        = (H - q) + inflow;
        out[1 + 14 * 1024 + 1024 + b] = q;
    }
}

extern "C" void kernel_launch(void* const* d_in, const int* in_sizes, int n_in,
                              void* d_out, int out_size, void* d_ws, size_t ws_size,
                              hipStream_t stream)
{
    (void)in_sizes; (void)n_in; (void)out_size; (void)ws_size;
    const float* H0     = (const float*)d_in[0];
    const float* Hmid   = (const float*)d_in[1];
    const float* Hlast  = (const float*)d_in[2];
    const float* S0     = (const float*)d_in[3];
    const float* Smid   = (const float*)d_in[4];
    const float* Slast  = (const float*)d_in[5];
    const float* th0    = (const float*)d_in[6];
    const float* thmid  = (const float*)d_in[7];
    const float* thlast = (const float*)d_in[8];
    const float* precip = (const float*)d_in[9];
    float* out = (float*)d_out;
    float* PA  = (float*)d_ws;                 // NPART x 1024 partials (ping)
    float* PB  = PA + (size_t)NPART * 1024;    // pong

    void* args[] = { &H0, &Hmid, &Hlast, &S0, &Smid, &Slast,
                     &th0, &thmid, &thlast, &precip, &out, &PA, &PB };
    hipError_t err = hipLaunchCooperativeKernel((const void*)cascade_kernel,
                                                dim3(256), dim3(256), args, 0, stream);
    if (err != hipSuccess) {
        layer0_kernel<<<1, 64, 0, stream>>>(H0, S0, th0, precip, out, PA);
        float* cur = PA; float* nxt = PB; int npart = 1;
        for (int l = 0; l < 14; ++l) {
            mid_kernel<<<256, 256, 0, stream>>>(Hmid + (size_t)l * 1024,
                                                Smid + (size_t)l * 1024 * 1024 * 2,
                                                thmid + (size_t)l * 1024 * 1024,
                                                cur, npart, nxt,
                                                out + 1 + (size_t)l * 1024, precip);
            float* t = cur; cur = nxt; nxt = t; npart = NPART;
        }
        last_kernel<<<256, 256, 0, stream>>>(Hlast, Slast, thlast, cur, precip, out);
    }
}

// Round 4
// 763.570 us; speedup vs baseline: 1.0762x; 1.0762x over previous
//
#include <hip/hip_runtime.h>
#include <hip/hip_cooperative_groups.h>
#include <math.h>

namespace cg = cooperative_groups;

#define TWO_G 19.6f   // 2*9.8, matches jnp's folded 2.0*G constant
#define NPART 256     // partial-sum rows (== grid size of the mid phase)

__device__ __forceinline__ float flow_q(float th, float d, float a) {
    // matches reference association: (theta * sqrt(2*G*h)) * area
    return th * sqrtf(TWO_G * d) * a;
}

__device__ __forceinline__ float wave_sum(float v) {
#pragma unroll
    for (int o = 32; o > 0; o >>= 1) v += __shfl_xor(v, o);
    return v;
}

// uniform-index broadcast (j is wave-uniform at each use site)
__device__ __forceinline__ float lane_bcast(float v, int j) {
    return __int_as_float(__builtin_amdgcn_readlane(__float_as_int(v), j));
}

// async global->LDS DMA, 16B/lane: lds dest = wave-uniform base (+ lane*16 by HW).
// Zero VGPRs held across the solve -> the round-1/2 spill mode cannot occur.
__device__ __forceinline__ void dma16(const void* g, void* l) {
    __builtin_amdgcn_global_load_lds(
        (const __attribute__((address_space(1))) unsigned int*)g,
        (__attribute__((address_space(3))) unsigned int*)l, 16, 0, 0);
}

// ---------------- register-sourced serial solve (layer0 + fallback path) --------
__device__ __forceinline__ float solve_serial(float H, float inflow, int lane,
                                              float2 (&sv)[16], float (&tv)[16],
                                              float* acc) {
    float h0 = lane_bcast(sv[0].x, 0);
    float a0 = lane_bcast(sv[0].y, 0);
    float t0 = lane_bcast(tv[0], 0);
    float d0 = (H + inflow) - h0;
    float q0 = (d0 > 0.0f) ? flow_q(t0, d0, a0) : 0.0f;
    float cum = q0;
    float u   = H - 0.5f * cum;
    if (lane == 0 && q0 != 0.0f) atomicAdd(&acc[0], q0);

#pragma unroll
    for (int c = 0; c < 16; ++c) {
        float2 s = sv[c];
        unsigned long long avail = (c == 0) ? ~1ull : ~0ull;   // spigot 0 already done
        unsigned long long cand  = __ballot(s.x < u) & avail;
        float qmine = 0.0f;
        while (cand) {
            int j = __builtin_ctzll(cand);
            float hj = lane_bcast(s.x, j);
            float aj = lane_bcast(s.y, j);
            float tj = lane_bcast(tv[c], j);
            float d = u - hj;                    // > 0 by ballot
            float q = flow_q(tj, d, aj);
            cum += q;
            u = H - 0.5f * cum;
            if (lane == j) qmine = q;
            if (j >= 63) break;
            avail &= (~0ull << (j + 1));
            cand = __ballot(s.x < u) & avail;    // u decreased: subset of old cand
        }
        if (qmine != 0.0f) atomicAdd(&acc[c * 64 + lane], qmine);
    }
    return cum;
}

// ---------------- LDS-sourced serial solve (fused mid layers) --------------------
// Identical arithmetic/order; global->LDS->reg routing is bit-exact for f32.
// 1-chunk-ahead ds_read prefetch keeps LDS latency off the serial chain.
__device__ __forceinline__ float solve_lds(float H, float inflow, int lane,
                                           const char* buf, float* acc) {
    const float2* Sb = (const float2*)buf;          // 1024 float2 (row layout)
    const float*  Tb = (const float*)(buf + 8192);  // 1024 float

    float2 s_cur = Sb[lane];
    float  t_cur = Tb[lane];

    float h0 = lane_bcast(s_cur.x, 0);
    float a0 = lane_bcast(s_cur.y, 0);
    float t0 = lane_bcast(t_cur, 0);
    float d0 = (H + inflow) - h0;
    float q0 = (d0 > 0.0f) ? flow_q(t0, d0, a0) : 0.0f;
    float cum = q0;
    float u   = H - 0.5f * cum;
    if (lane == 0 && q0 != 0.0f) atomicAdd(&acc[0], q0);

#pragma unroll
    for (int c = 0; c < 16; ++c) {
        float2 s = s_cur;
        float  t = t_cur;
        if (c < 15) {                               // prefetch next chunk off-chain
            s_cur = Sb[(c + 1) * 64 + lane];
            t_cur = Tb[(c + 1) * 64 + lane];
        }
        unsigned long long avail = (c == 0) ? ~1ull : ~0ull;
        unsigned long long cand  = __ballot(s.x < u) & avail;
        float qmine = 0.0f;
        while (cand) {
            int j = __builtin_ctzll(cand);
            float hj = lane_bcast(s.x, j);
            float aj = lane_bcast(s.y, j);
            float tj = lane_bcast(t, j);
            float d = u - hj;
            float q = flow_q(tj, d, aj);
            cum += q;
            u = H - 0.5f * cum;
            if (lane == j) qmine = q;
            if (j >= 63) break;
            avail &= (~0ull << (j + 1));
            cand = __ballot(s.x < u) & avail;
        }
        if (qmine != 0.0f) atomicAdd(&acc[c * 64 + lane], qmine);
    }
    return cum;
}

// ---- layer 0: single head bucket, 1024 spigots, one wave; dense q row -> P0 ----
__device__ __forceinline__ void layer0_body(const float* __restrict__ H0p,
                                            const float* __restrict__ S0,
                                            const float* __restrict__ theta0,
                                            const float* __restrict__ precip,
                                            float* __restrict__ out,
                                            float* __restrict__ P0, int lane) {
    const float H  = H0p[0];
    const float pl = precip[0] * 0.0625f;        // precip / 16 (exact)
    const float2* S2 = (const float2*)S0;
    float2 sv[16]; float tv[16];
#pragma unroll
    for (int c = 0; c < 16; ++c) { sv[c] = S2[c * 64 + lane]; tv[c] = theta0[c * 64 + lane]; }

    float h0 = lane_bcast(sv[0].x, 0);
    float a0 = lane_bcast(sv[0].y, 0);
    float t0 = lane_bcast(tv[0], 0);
    float d0 = (H + pl) - h0;
    float q0 = (d0 > 0.0f) ? flow_q(t0, d0, a0) : 0.0f;
    float cum = q0;
    float u   = H - 0.5f * cum;
    if (lane == 0) P0[0] = q0;

#pragma unroll
    for (int c = 0; c < 16; ++c) {
        int i = c * 64 + lane;
        float2 s = sv[c];
        unsigned long long avail = (c == 0) ? ~1ull : ~0ull;
        unsigned long long cand  = __ballot(s.x < u) & avail;
        float qmine = 0.0f;
        while (cand) {
            int j = __builtin_ctzll(cand);
            float hj = lane_bcast(s.x, j);
            float aj = lane_bcast(s.y, j);
            float tj = lane_bcast(tv[c], j);
            float d = u - hj;
            float q = flow_q(tj, d, aj);
            cum += q;
            u = H - 0.5f * cum;
            if (lane == j) qmine = q;
            if (j >= 63) break;
            avail &= (~0ull << (j + 1));
            cand = __ballot(s.x < u) & avail;
        }
        if (i > 0) P0[i] = qmine;
    }
    if (lane == 0) out[0] = (H - cum) + pl;      // H0_new
}

// ---- the whole cascade: 1 cooperative kernel, 256 blocks (1/CU), static 52 KB --
// Single 12 KB LDS buffer per wave, staged by async global_load_lds for layer l+1
// AFTER layer l's solve (post-__syncthreads => this wave's ds_reads all retired).
// The s_barrier inside grid.sync drains vmcnt(0) => DMA complete before next solve.
__global__ __launch_bounds__(256, 1)
void cascade_kernel(const float* __restrict__ H0p, const float* __restrict__ Hmid,
                    const float* __restrict__ Hlast, const float* __restrict__ S0,
                    const float* __restrict__ Smid, const float* __restrict__ Slast,
                    const float* __restrict__ th0, const float* __restrict__ thmid,
                    const float* __restrict__ thlast, const float* __restrict__ precip,
                    float* __restrict__ out, float* __restrict__ PA, float* __restrict__ PB)
{
    cg::grid_group grid = cg::this_grid();
    __shared__ float acc[1024];                     // block-level q accumulator
    __shared__ __align__(16) char sbuf[4][12288];   // per-wave: S row 8 KB + theta 4 KB

    const int tid  = threadIdx.x;
    const int lane = tid & 63;
    const int w    = tid >> 6;
    const int bid  = blockIdx.x;
    const int b    = bid * 4 + w;               // bucket<->wave mapping (unchanged)

#pragma unroll
    for (int r = 0; r < 4; ++r) acc[r * 256 + tid] = 0.0f;

    const float pb = precip[0] * (0.0625f / 1024.0f);   // exact: 2^-14 * precip

    // ---- pre-loop: DMA-stage mid layer 0 for this wave's bucket ----
    {
        char* dst = sbuf[w];
        const char* gS = (const char*)Smid + (size_t)b * 8192;
        const char* gT = (const char*)thmid + (size_t)b * 4096;
#pragma unroll
        for (int i = 0; i < 8; ++i) dma16(gS + i * 1024 + lane * 16, dst + i * 1024);
#pragma unroll
        for (int i = 0; i < 4; ++i) dma16(gT + i * 1024 + lane * 16, dst + 8192 + i * 1024);
    }
    // head bucket runs on block 0 / wave 0 while all staging DMAs fly
    if (bid == 0 && w == 0)
        layer0_body(H0p, S0, th0, precip, out, PA, lane);
    grid.sync();                                // barrier drains vmcnt(0) + publishes PA

#pragma unroll 1
    for (int l = 0; l < 14; ++l) {
        const float* Pin = (l & 1) ? PB : PA;
        float*       Pou = (l & 1) ? PA : PB;

        // 1) inflow gather + reduce (4 L2/L3 loads + butterfly)
        float part = 0.0f;
        if (l == 0) {
            if (lane == 0) part = Pin[b];       // layer0 wrote a single row
        } else {
#pragma unroll
            for (int k = 0; k < 4; ++k) part += Pin[(size_t)(k * 64 + lane) * 1024 + b];
        }
        const float H      = Hmid[(size_t)l * 1024 + b];
        const float inflow = pb + wave_sum(part);

        // 2) serial solve from this wave's LDS buffer (DMA'd last iteration)
        const float cum = solve_lds(H, inflow, lane, sbuf[w], acc);
        if (lane == 0) out[1 + (size_t)l * 1024 + b] = (H - cum) + inflow;

        __syncthreads();                        // acc complete; my ds_reads all retired

        // 3) issue next layer's staging DMA into the SAME slot (only this wave
        //    reads it; completion = vmcnt(0) drain at grid.sync's s_barrier).
        //    Overlaps the partial store + grid.sync arrival spread.
        if (l < 13) {
            char* dst = sbuf[w];
            const char* gS = (const char*)Smid + (size_t)(l + 1) * 8388608 + (size_t)b * 8192;
            const char* gT = (const char*)thmid + (size_t)(l + 1) * 4194304 + (size_t)b * 4096;
#pragma unroll
            for (int i = 0; i < 8; ++i) dma16(gS + i * 1024 + lane * 16, dst + i * 1024);
#pragma unroll
            for (int i = 0; i < 4; ++i) dma16(gT + i * 1024 + lane * 16, dst + 8192 + i * 1024);
        }

        // 4) dense partial row -> global, re-arm acc, publish grid-wide
#pragma unroll
        for (int r = 0; r < 4; ++r) {
            const int idx = r * 256 + tid;
            Pou[(size_t)bid * 1024 + idx] = acc[idx];
            acc[idx] = 0.0f;
        }
        grid.sync();
    }

    // ---- last layer: 1 spigot per bucket (l=13 wrote PA) ----
    {
        float part = 0.0f;
#pragma unroll
        for (int k = 0; k < 4; ++k) part += PA[(size_t)(k * 64 + lane) * 1024 + b];
        const float inflow = pb + wave_sum(part);
        if (lane == 0) {
            const float  Hv = Hlast[b];
            const float2 s  = ((const float2*)Slast)[b];
            const float  d  = (Hv + inflow) - s.x;
            const float  q  = (d > 0.0f) ? flow_q(thlast[b], d, s.y) : 0.0f;
            out[1 + 14 * 1024 + b]        = (Hv - q) + inflow;   // H_last_new
            out[1 + 14 * 1024 + 1024 + b] = q;                   // q_last
        }
    }
}

// ================= fallback: 16-kernel pipeline (round-0 numerics) ==============
__device__ __forceinline__ void prefetch_row(const float2* __restrict__ S2,
                                             const float* __restrict__ th, int lane,
                                             float2 (&sv)[16], float (&tv)[16]) {
#pragma unroll
    for (int c = 0; c < 16; ++c) { sv[c] = S2[c * 64 + lane]; tv[c] = th[c * 64 + lane]; }
}

__global__ __launch_bounds__(64)
void layer0_kernel(const float* __restrict__ H0p, const float* __restrict__ S0,
                   const float* __restrict__ theta0, const float* __restrict__ precip,
                   float* __restrict__ out, float* __restrict__ P0)
{
    layer0_body(H0p, S0, theta0, precip, out, P0, threadIdx.x);
}

__global__ __launch_bounds__(256)
void mid_kernel(const float* __restrict__ Hl, const float* __restrict__ Sl,
                const float* __restrict__ thl, const float* __restrict__ Pin,
                int npart, float* __restrict__ Pout, float* __restrict__ outl,
                const float* __restrict__ precip)
{
    __shared__ float acc[1024];
    const int tid  = threadIdx.x;
    const int lane = tid & 63;
    const int b    = blockIdx.x * 4 + (tid >> 6);

#pragma unroll
    for (int r = 0; r < 4; ++r) acc[r * 256 + tid] = 0.0f;
    __syncthreads();

    const float pb = precip[0] * (0.0625f / 1024.0f);

    float part = 0.0f;
    for (int k = lane; k < npart; k += 64) part += Pin[(size_t)k * 1024 + b];

    float2 sv[16]; float tv[16];
    prefetch_row((const float2*)Sl + (size_t)b * 1024, thl + (size_t)b * 1024, lane, sv, tv);

    const float H      = Hl[b];
    const float inflow = pb + wave_sum(part);
    const float cum    = solve_serial(H, inflow, lane, sv, tv, acc);
    if (lane == 0) outl[b] = (H - cum) + inflow;

    __syncthreads();
#pragma unroll
    for (int r = 0; r < 4; ++r)
        Pout[(size_t)blockIdx.x * 1024 + r * 256 + tid] = acc[r * 256 + tid];
}

__global__ __launch_bounds__(256)
void last_kernel(const float* __restrict__ Hlast, const float* __restrict__ Slast,
                 const float* __restrict__ thlast, const float* __restrict__ Pin,
                 const float* __restrict__ precip, float* __restrict__ out)
{
    const int lane = threadIdx.x & 63;
    const int b    = blockIdx.x * 4 + (threadIdx.x >> 6);
    const float pb = precip[0] * (0.0625f / 1024.0f);

    float part = 0.0f;
#pragma unroll
    for (int k = 0; k < NPART / 64; ++k) part += Pin[(size_t)(k * 64 + lane) * 1024 + b];
    float inflow = pb + wave_sum(part);

    if (lane == 0) {
        float H = Hlast[b];
        float2 s = ((const float2*)Slast)[b];
        float d = (H + inflow) - s.x;
        float q = (d > 0.0f) ? flow_q(thlast[b], d, s.y) : 0.0f;
        out[1 + 14 * 1024 + b]        = (H - q) + inflow;
        out[1 + 14 * 1024 + 1024 + b] = q;
    }
}

extern "C" void kernel_launch(void* const* d_in, const int* in_sizes, int n_in,
                              void* d_out, int out_size, void* d_ws, size_t ws_size,
                              hipStream_t stream)
{
    (void)in_sizes; (void)n_in; (void)out_size; (void)ws_size;
    const float* H0     = (const float*)d_in[0];
    const float* Hmid   = (const float*)d_in[1];
    const float* Hlast  = (const float*)d_in[2];
    const float* S0     = (const float*)d_in[3];
    const float* Smid   = (const float*)d_in[4];
    const float* Slast  = (const float*)d_in[5];
    const float* th0    = (const float*)d_in[6];
    const float* thmid  = (const float*)d_in[7];
    const float* thlast = (const float*)d_in[8];
    const float* precip = (const float*)d_in[9];
    float* out = (float*)d_out;
    float* PA  = (float*)d_ws;                 // NPART x 1024 partials (ping)
    float* PB  = PA + (size_t)NPART * 1024;    // pong

    void* args[] = { &H0, &Hmid, &Hlast, &S0, &Smid, &Slast,
                     &th0, &thmid, &thlast, &precip, &out, &PA, &PB };
    hipError_t err = hipLaunchCooperativeKernel((const void*)cascade_kernel,
                                                dim3(256), dim3(256), args, 0, stream);
    if (err != hipSuccess) {
        layer0_kernel<<<1, 64, 0, stream>>>(H0, S0, th0, precip, out, PA);
        float* cur = PA; float* nxt = PB; int npart = 1;
        for (int l = 0; l < 14; ++l) {
            mid_kernel<<<256, 256, 0, stream>>>(Hmid + (size_t)l * 1024,
                                                Smid + (size_t)l * 1024 * 1024 * 2,
                                                thmid + (size_t)l * 1024 * 1024,
                                                cur, npart, nxt,
                                                out + 1 + (size_t)l * 1024, precip);
            float* t = cur; cur = nxt; nxt = t; npart = NPART;
        }
        last_kernel<<<256, 256, 0, stream>>>(Hlast, Slast, thlast, cur, precip, out);
    }
}

// Round 5
// 318.031 us; speedup vs baseline: 2.5840x; 2.4009x over previous
//
#include <hip/hip_runtime.h>
#include <math.h>

#define TWO_G 19.6f   // 2*9.8, matches jnp's folded 2.0*G constant

// ---- grid-barrier state (module .bss, zero-initialized at load).
// Invariant: g_cnt == 256 * g_gen at every kernel boundary (each run does
// exactly 15 barriers of 256 arrivals), so back-to-back iterations, graph
// replays and rocprof re-runs all start from a consistent state.
__device__ __attribute__((aligned(256))) unsigned g_cnt;
__device__ __attribute__((aligned(256))) unsigned g_gen;

__device__ __forceinline__ float flow_q(float th, float d, float a) {
    // matches reference association: (theta * sqrt(2*G*h)) * area
    return th * sqrtf(TWO_G * d) * a;
}

__device__ __forceinline__ float wave_sum(float v) {
#pragma unroll
    for (int o = 32; o > 0; o >>= 1) v += __shfl_xor(v, o);
    return v;
}

// uniform-index broadcast (j is wave-uniform at each use site)
__device__ __forceinline__ float lane_bcast(float v, int j) {
    return __int_as_float(__builtin_amdgcn_readlane(__float_as_int(v), j));
}

// agent-scope (device-coherent, sc1 -> MALL) load/store: all cross-block data
// uses these, so the grid barrier needs NO L2 writeback/invalidate at all.
__device__ __forceinline__ float ld_agent(const float* p) {
    return __hip_atomic_load(p, __ATOMIC_RELAXED, __HIP_MEMORY_SCOPE_AGENT);
}
__device__ __forceinline__ void st_agent(float* p, float v) {
    __hip_atomic_store(p, v, __ATOMIC_RELAXED, __HIP_MEMORY_SCOPE_AGENT);
}

// async global->LDS DMA, 16B/lane: lds dest = wave-uniform base (+ lane*16 by HW)
__device__ __forceinline__ void dma16(const void* g, void* l) {
    __builtin_amdgcn_global_load_lds(
        (const __attribute__((address_space(1))) unsigned int*)g,
        (__attribute__((address_space(3))) unsigned int*)l, 16, 0, 0);
}

// Lean sense-free grid barrier: monotone arrival counter + generation word,
// RELAXED agent atomics only. Caller must have vmcnt-drained its sc1 stores
// BEFORE calling (that drain is the release; sc1 loads after are the acquire).
__device__ __forceinline__ void grid_barrier(unsigned& cbase, unsigned& gtarget) {
    __syncthreads();
    if (threadIdx.x == 0) {
        gtarget += 1u;
        unsigned old = __hip_atomic_fetch_add(&g_cnt, 1u, __ATOMIC_RELAXED,
                                              __HIP_MEMORY_SCOPE_AGENT);
        if (old - cbase == 255u) {
            // I am the 256th arriver of this round: release everyone.
            __hip_atomic_fetch_add(&g_gen, 1u, __ATOMIC_RELAXED,
                                   __HIP_MEMORY_SCOPE_AGENT);
        } else {
            while ((int)(__hip_atomic_load(&g_gen, __ATOMIC_RELAXED,
                                           __HIP_MEMORY_SCOPE_AGENT) - gtarget) < 0)
                __builtin_amdgcn_s_sleep(2);
        }
        cbase += 256u;
    }
    __syncthreads();
    asm volatile("" ::: "memory");   // compiler fence: nothing hoists above release
}

// ---------------- LDS-sourced serial solve (identical arithmetic/order) ---------
__device__ __forceinline__ float solve_lds(float H, float inflow, int lane,
                                           const char* buf, float* acc) {
    const float2* Sb = (const float2*)buf;          // 1024 float2 (row layout)
    const float*  Tb = (const float*)(buf + 8192);  // 1024 float

    float2 s_cur = Sb[lane];
    float  t_cur = Tb[lane];

    float h0 = lane_bcast(s_cur.x, 0);
    float a0 = lane_bcast(s_cur.y, 0);
    float t0 = lane_bcast(t_cur, 0);
    float d0 = (H + inflow) - h0;
    float q0 = (d0 > 0.0f) ? flow_q(t0, d0, a0) : 0.0f;
    float cum = q0;
    float u   = H - 0.5f * cum;
    if (lane == 0 && q0 != 0.0f) atomicAdd(&acc[0], q0);

#pragma unroll
    for (int c = 0; c < 16; ++c) {
        float2 s = s_cur;
        float  t = t_cur;
        if (c < 15) {                               // prefetch next chunk off-chain
            s_cur = Sb[(c + 1) * 64 + lane];
            t_cur = Tb[(c + 1) * 64 + lane];
        }
        unsigned long long avail = (c == 0) ? ~1ull : ~0ull;   // spigot 0 done
        unsigned long long cand  = __ballot(s.x < u) & avail;
        float qmine = 0.0f;
        while (cand) {
            int j = __builtin_ctzll(cand);
            float hj = lane_bcast(s.x, j);
            float aj = lane_bcast(s.y, j);
            float tj = lane_bcast(t, j);
            float d = u - hj;                       // > 0 by ballot
            float q = flow_q(tj, d, aj);
            cum += q;
            u = H - 0.5f * cum;
            if (lane == j) qmine = q;
            if (j >= 63) break;
            avail &= (~0ull << (j + 1));
            cand = __ballot(s.x < u) & avail;       // u decreased: subset of old
        }
        if (qmine != 0.0f) atomicAdd(&acc[c * 64 + lane], qmine);
    }
    return cum;
}

// ---- layer 0: single head bucket, 1024 spigots, one wave; q row -> P0 (agent) --
__device__ __forceinline__ void layer0_body(const float* __restrict__ H0p,
                                            const float* __restrict__ S0,
                                            const float* __restrict__ theta0,
                                            const float* __restrict__ precip,
                                            float* __restrict__ out,
                                            float* __restrict__ P0, int lane) {
    const float H  = H0p[0];
    const float pl = precip[0] * 0.0625f;        // precip / 16 (exact)
    const float2* S2 = (const float2*)S0;
    float2 sv[16]; float tv[16];
#pragma unroll
    for (int c = 0; c < 16; ++c) { sv[c] = S2[c * 64 + lane]; tv[c] = theta0[c * 64 + lane]; }

    float h0 = lane_bcast(sv[0].x, 0);
    float a0 = lane_bcast(sv[0].y, 0);
    float t0 = lane_bcast(tv[0], 0);
    float d0 = (H + pl) - h0;
    float q0 = (d0 > 0.0f) ? flow_q(t0, d0, a0) : 0.0f;
    float cum = q0;
    float u   = H - 0.5f * cum;
    if (lane == 0) st_agent(&P0[0], q0);

#pragma unroll
    for (int c = 0; c < 16; ++c) {
        int i = c * 64 + lane;
        float2 s = sv[c];
        unsigned long long avail = (c == 0) ? ~1ull : ~0ull;
        unsigned long long cand  = __ballot(s.x < u) & avail;
        float qmine = 0.0f;
        while (cand) {
            int j = __builtin_ctzll(cand);
            float hj = lane_bcast(s.x, j);
            float aj = lane_bcast(s.y, j);
            float tj = lane_bcast(tv[c], j);
            float d = u - hj;
            float q = flow_q(tj, d, aj);
            cum += q;
            u = H - 0.5f * cum;
            if (lane == j) qmine = q;
            if (j >= 63) break;
            avail &= (~0ull << (j + 1));
            cand = __ballot(s.x < u) & avail;
        }
        if (i > 0) st_agent(&P0[i], qmine);
    }
    if (lane == 0) out[0] = (H - cum) + pl;      // H0_new
}

// ---- the whole cascade: 1 regular kernel, 256 blocks (1/CU), custom barrier ----
__global__ __launch_bounds__(256, 1)
void cascade_kernel(const float* __restrict__ H0p, const float* __restrict__ Hmid,
                    const float* __restrict__ Hlast, const float* __restrict__ S0,
                    const float* __restrict__ Smid, const float* __restrict__ Slast,
                    const float* __restrict__ th0, const float* __restrict__ thmid,
                    const float* __restrict__ thlast, const float* __restrict__ precip,
                    float* __restrict__ out, float* __restrict__ PA, float* __restrict__ PB)
{
    __shared__ float acc[1024];                     // block-level q accumulator
    __shared__ __align__(16) char sbuf[4][12288];   // per-wave: S row 8 KB + theta 4 KB

    const int tid  = threadIdx.x;
    const int lane = tid & 63;
    const int w    = tid >> 6;
    const int bid  = blockIdx.x;
    const int b    = bid * 4 + w;               // bucket<->wave mapping (unchanged)

    // barrier bookkeeping: true base is 256*gen (gen is stable until ALL blocks
    // of this launch -- including me -- arrive at barrier 1, so this read is safe)
    unsigned cbase = 0, gtarget = 0;
    if (tid == 0) {
        gtarget = __hip_atomic_load(&g_gen, __ATOMIC_RELAXED, __HIP_MEMORY_SCOPE_AGENT);
        cbase   = gtarget * 256u;
    }

#pragma unroll
    for (int r = 0; r < 4; ++r) acc[r * 256 + tid] = 0.0f;

    const float pb = precip[0] * (0.0625f / 1024.0f);   // exact: 2^-14 * precip

    // ---- pre-loop: DMA-stage mid layer 0 for this wave's bucket ----
    {
        char* dst = sbuf[w];
        const char* gS = (const char*)Smid + (size_t)b * 8192;
        const char* gT = (const char*)thmid + (size_t)b * 4096;
#pragma unroll
        for (int i = 0; i < 8; ++i) dma16(gS + i * 1024 + lane * 16, dst + i * 1024);
#pragma unroll
        for (int i = 0; i < 4; ++i) dma16(gT + i * 1024 + lane * 16, dst + 8192 + i * 1024);
    }
    // head bucket runs on block 0 / wave 0 while all staging DMAs fly
    if (bid == 0 && w == 0)
        layer0_body(H0p, S0, th0, precip, out, PA, lane);
    asm volatile("s_waitcnt vmcnt(0)" ::: "memory");   // P0 stores + DMA drained
    grid_barrier(cbase, gtarget);

#pragma unroll 1
    for (int l = 0; l < 14; ++l) {
        const float* Pin = (l & 1) ? PB : PA;
        float*       Pou = (l & 1) ? PA : PB;

        // 1) inflow gather (agent loads -> MALL, always coherent) + reduce
        float part = 0.0f;
        if (l == 0) {
            if (lane == 0) part = ld_agent(&Pin[b]);    // layer0 wrote one row
        } else {
#pragma unroll
            for (int k = 0; k < 4; ++k)
                part += ld_agent(&Pin[(size_t)(k * 64 + lane) * 1024 + b]);
        }
        const float H      = Hmid[(size_t)l * 1024 + b];
        const float inflow = pb + wave_sum(part);

        // 2) serial solve from this wave's LDS buffer (DMA'd last iteration)
        const float cum = solve_lds(H, inflow, lane, sbuf[w], acc);
        if (lane == 0) out[1 + (size_t)l * 1024 + b] = (H - cum) + inflow;

        __syncthreads();                        // all waves' acc atomics complete

        // 3) dense partial row -> global (agent stores), re-arm acc
#pragma unroll
        for (int r = 0; r < 4; ++r) {
            const int idx = r * 256 + tid;
            st_agent(&Pou[(size_t)bid * 1024 + idx], acc[idx]);
            acc[idx] = 0.0f;
        }
        asm volatile("" ::: "memory");

        // 4) issue next layer's staging DMA, then wait with vmcnt(12): the 4
        //    partial stores (older, in-order retirement) are drained while the
        //    12 DMAs stay in flight across the barrier spin (T4-style).
        if (l < 13) {
            char* dst = sbuf[w];
            const char* gS = (const char*)Smid + (size_t)(l + 1) * 8388608 + (size_t)b * 8192;
            const char* gT = (const char*)thmid + (size_t)(l + 1) * 4194304 + (size_t)b * 4096;
#pragma unroll
            for (int i = 0; i < 8; ++i) dma16(gS + i * 1024 + lane * 16, dst + i * 1024);
#pragma unroll
            for (int i = 0; i < 4; ++i) dma16(gT + i * 1024 + lane * 16, dst + 8192 + i * 1024);
            asm volatile("s_waitcnt vmcnt(12)" ::: "memory");
        } else {
            asm volatile("s_waitcnt vmcnt(0)" ::: "memory");
        }

        grid_barrier(cbase, gtarget);           // partials published grid-wide
        asm volatile("s_waitcnt vmcnt(0)" ::: "memory");   // DMA landed in LDS
    }

    // ---- last layer: 1 spigot per bucket (l=13 wrote PA) ----
    {
        float part = 0.0f;
#pragma unroll
        for (int k = 0; k < 4; ++k)
            part += ld_agent(&PA[(size_t)(k * 64 + lane) * 1024 + b]);
        const float inflow = pb + wave_sum(part);
        if (lane == 0) {
            const float  Hv = Hlast[b];
            const float2 s  = ((const float2*)Slast)[b];
            const float  d  = (Hv + inflow) - s.x;
            const float  q  = (d > 0.0f) ? flow_q(thlast[b], d, s.y) : 0.0f;
            out[1 + 14 * 1024 + b]        = (Hv - q) + inflow;   // H_last_new
            out[1 + 14 * 1024 + 1024 + b] = q;                   // q_last
        }
    }
}

extern "C" void kernel_launch(void* const* d_in, const int* in_sizes, int n_in,
                              void* d_out, int out_size, void* d_ws, size_t ws_size,
                              hipStream_t stream)
{
    (void)in_sizes; (void)n_in; (void)out_size; (void)ws_size;
    const float* H0     = (const float*)d_in[0];
    const float* Hmid   = (const float*)d_in[1];
    const float* Hlast  = (const float*)d_in[2];
    const float* S0     = (const float*)d_in[3];
    const float* Smid   = (const float*)d_in[4];
    const float* Slast  = (const float*)d_in[5];
    const float* th0    = (const float*)d_in[6];
    const float* thmid  = (const float*)d_in[7];
    const float* thlast = (const float*)d_in[8];
    const float* precip = (const float*)d_in[9];
    float* out = (float*)d_out;
    float* PA  = (float*)d_ws;                 // 256 x 1024 partials (ping)
    float* PB  = PA + (size_t)256 * 1024;      // pong

    // Regular launch: 256 blocks x 53 KB LDS on 256 CUs are trivially
    // co-resident (3 fit per CU), so the cooperative-launch residency
    // guarantee -- and its ~175 us/iteration overhead -- is not needed.
    cascade_kernel<<<dim3(256), dim3(256), 0, stream>>>(
        H0, Hmid, Hlast, S0, Smid, Slast, th0, thmid, thlast, precip, out, PA, PB);
}